// Round 18
// baseline (195.533 us; speedup 1.0000x reference)
//
#include <hip/hip_runtime.h>
#include <math.h>

// MLA decode attention, flash-decoding split + bf16 MFMA core.
// B=64, H=16, latent D=576, V=512, MAX_LEN=4096. fp32 in/out.
//
// R18 vs R16 (118.5us): slim tile TR=16 -> 3 blocks/CU (12 waves).
//  - R14's 3-block attempt failed on PV u16-gather bank conflicts, not
//    occupancy. This keeps the PROVEN dual layout (K_s row-major + Vt
//    transposed, wide b64 reads) and just halves the tile: LDS = 18688
//    (K_s 16x584) + 20480 (Vt 512x20) + 2560 (P_s) = 41728 B -> 3 blk/CU.
//  - PV keeps mfma 16x16x32 with the upper K-half zero-padded (lanes g>=2
//    contribute zeros): MFMA is ~1% of runtime, half-utilization there is
//    free, and no new intrinsic/layout risk.
//  - Stage is synchronous (no reg prefetch) to fit ~155 VGPR under
//    __launch_bounds__(256,3); 3-deep cross-block TLP hides stage latency
//    (R10's in-block async was only worth 13us at 2-deep).
//  - Alignment/banks verified: all LDS accesses 8/16B-aligned; Vt VP=20
//    16-lane reads conflict-free; K_s 2-way (free per m136).
//  Kept: nchunk=16, log2 softmax w/ skip-rescale + deferred l, P_s
//  transpose, setprio, OOB clamp, bf16 ws_o + unrolled reduce.

typedef __attribute__((ext_vector_type(8))) short bf16x8;
typedef __attribute__((ext_vector_type(4))) float f32x4;

namespace {
constexpr int NB = 64, NH = 16, MAXLEN = 4096, D = 576, DV = 512;
constexpr int TR = 16;    // tile rows
constexpr int KP = 584;   // K_s row stride (bf16): 1168 B rows, 16B-aligned
constexpr int VP = 20;    // Vt row stride (bf16): 40 B rows, 8B-aligned
constexpr int PP = 20;    // P_s row stride (bf16): 40 B rows
constexpr float SCALE_LOG2E = 0.041666666666666664f * 1.4426950408889634f;
constexpr float NEGINF = -1e30f;
}

__device__ __forceinline__ uint32_t cvtpk(float a, float b) {
    uint32_t r;
    asm("v_cvt_pk_bf16_f32 %0, %1, %2" : "=v"(r) : "v"(a), "v"(b));
    return r;   // low16 = bf16(a), high16 = bf16(b)
}

union FragAB { bf16x8 v; uint32_t u[4]; uint2 d[2]; };

__global__ __launch_bounds__(256, 3)
void mla_mfma(const float* __restrict__ qg, const float* __restrict__ kvnew,
              const float* __restrict__ cache, const int* __restrict__ lens,
              unsigned short* __restrict__ ws_o, float* __restrict__ ws_ml,
              int nchunk, int chunk)
{
    const int c = blockIdx.x, b = blockIdx.y;
    const int total = lens[b] + 1;
    const int start = c * chunk;
    if (start >= total) return;               // uniform, before any barrier
    const int end = min(start + chunk, total);
    const int newpos = total - 1;

    __shared__ short K_s[TR * KP];            // 18688 B row-major bf16
    __shared__ short V_s[DV * VP];            // 20480 B Vt[v][r] bf16
    __shared__ short P_s[4 * 16 * PP];        //  2560 B  (total 41728)

    const int tid  = (int)threadIdx.x;
    const int wave = tid >> 6, lane = tid & 63;
    const int lr = lane & 15, g = lane >> 4;

    const float* vnew = kvnew + (size_t)b * D;
    const float* cb   = cache + (size_t)b * MAXLEN * D;

    // staging: wave w covers rows w*4..w*4+3; lane covers f4-col 64*it+lane
    const int rg = wave;
    const int cl = lane;

    // ---- Q A-frags: lane holds Q[h=lr][kc*32 + g*8 + j], scale folded ----
    FragAB qf[18];
    {
        const float* qrow = qg + ((size_t)b * NH + lr) * D + g * 8;
        #pragma unroll
        for (int kc = 0; kc < 18; ++kc) {
            float4 x = *(const float4*)(qrow + kc * 32);
            float4 y = *(const float4*)(qrow + kc * 32 + 4);
            qf[kc].u[0] = cvtpk(x.x * SCALE_LOG2E, x.y * SCALE_LOG2E);
            qf[kc].u[1] = cvtpk(x.z * SCALE_LOG2E, x.w * SCALE_LOG2E);
            qf[kc].u[2] = cvtpk(y.x * SCALE_LOG2E, y.y * SCALE_LOG2E);
            qf[kc].u[3] = cvtpk(y.z * SCALE_LOG2E, y.w * SCALE_LOG2E);
        }
    }

    f32x4 acc[8];
    #pragma unroll
    for (int i = 0; i < 8; ++i) acc[i] = (f32x4){0.f, 0.f, 0.f, 0.f};
    float m2[4] = {NEGINF, NEGINF, NEGINF, NEGINF};
    float ll[4] = {0.f, 0.f, 0.f, 0.f};      // lane-local partial sums

    for (int r0 = start; r0 < end; r0 += TR) {
        __syncthreads();                      // prev round's LDS reads done

        // ---- stage 16 rows fp32 -> bf16, dual-write K_s + Vt ----
        {
            const int gr0 = r0 + rg * 4;
            const int r0c = min(gr0,     MAXLEN - 1);
            const int r1c = min(gr0 + 1, MAXLEN - 1);
            const int r2c = min(gr0 + 2, MAXLEN - 1);
            const int r3c = min(gr0 + 3, MAXLEN - 1);
            const float* s0 = (gr0     == newpos) ? vnew : (cb + (size_t)r0c * D);
            const float* s1 = (gr0 + 1 == newpos) ? vnew : (cb + (size_t)r1c * D);
            const float* s2 = (gr0 + 2 == newpos) ? vnew : (cb + (size_t)r2c * D);
            const float* s3 = (gr0 + 3 == newpos) ? vnew : (cb + (size_t)r3c * D);
            #pragma unroll
            for (int it = 0; it < 3; ++it) {
                const int cf = 64 * it + cl;
                if (cf < 144) {
                    float4 x0 = *(const float4*)(s0 + cf * 4);
                    float4 x1 = *(const float4*)(s1 + cf * 4);
                    float4 x2 = *(const float4*)(s2 + cf * 4);
                    float4 x3 = *(const float4*)(s3 + cf * 4);
                    uint2 w;
                    w.x = cvtpk(x0.x, x0.y); w.y = cvtpk(x0.z, x0.w);
                    *(uint2*)&K_s[(rg * 4 + 0) * KP + cf * 4] = w;
                    w.x = cvtpk(x1.x, x1.y); w.y = cvtpk(x1.z, x1.w);
                    *(uint2*)&K_s[(rg * 4 + 1) * KP + cf * 4] = w;
                    w.x = cvtpk(x2.x, x2.y); w.y = cvtpk(x2.z, x2.w);
                    *(uint2*)&K_s[(rg * 4 + 2) * KP + cf * 4] = w;
                    w.x = cvtpk(x3.x, x3.y); w.y = cvtpk(x3.z, x3.w);
                    *(uint2*)&K_s[(rg * 4 + 3) * KP + cf * 4] = w;
                    if (cf < 128) {
                        const int v0 = cf * 4;
                        w.x = cvtpk(x0.x, x1.x); w.y = cvtpk(x2.x, x3.x);
                        *(uint2*)&V_s[(v0 + 0) * VP + rg * 4] = w;
                        w.x = cvtpk(x0.y, x1.y); w.y = cvtpk(x2.y, x3.y);
                        *(uint2*)&V_s[(v0 + 1) * VP + rg * 4] = w;
                        w.x = cvtpk(x0.z, x1.z); w.y = cvtpk(x2.z, x3.z);
                        *(uint2*)&V_s[(v0 + 2) * VP + rg * 4] = w;
                        w.x = cvtpk(x0.w, x1.w); w.y = cvtpk(x2.w, x3.w);
                        *(uint2*)&V_s[(v0 + 3) * VP + rg * 4] = w;
                    }
                }
            }
        }
        __syncthreads();                      // stage visible to all waves

        // ---- scores: S[16h, 16r], one 16x16 tile ----
        f32x4 sc0 = (f32x4){0.f, 0.f, 0.f, 0.f};
        __builtin_amdgcn_s_setprio(1);
        #pragma unroll
        for (int kc = 0; kc < 18; ++kc) {
            FragAB kb0;
            kb0.v = *(const bf16x8*)&K_s[lr * KP + kc * 32 + g * 8];
            sc0 = __builtin_amdgcn_mfma_f32_16x16x32_bf16(qf[kc].v, kb0.v, sc0, 0, 0, 0);
        }
        __builtin_amdgcn_s_setprio(0);
        // mask invalid rows (lane's D-col = row r0+lr)
        if (r0 + lr >= end) sc0 = (f32x4){NEGINF, NEGINF, NEGINF, NEGINF};

        // ---- online softmax (log2 domain), skip-rescale + deferred l ----
        float mt[4];
        int grew = 0;
        #pragma unroll
        for (int i = 0; i < 4; ++i) {
            float t = sc0[i];
            t = fmaxf(t, __shfl_xor(t, 1));
            t = fmaxf(t, __shfl_xor(t, 2));
            t = fmaxf(t, __shfl_xor(t, 4));
            t = fmaxf(t, __shfl_xor(t, 8));
            mt[i] = t;
            grew |= (t > m2[i]) ? 1 : 0;
        }
        if (__any(grew)) {                   // wave-uniform branch
            float scl[4];
            #pragma unroll
            for (int i = 0; i < 4; ++i) {
                const float nm = fmaxf(m2[i], mt[i]);
                scl[i] = exp2f(m2[i] - nm);  // ==1 for non-growing groups
                m2[i] = nm;
                ll[i] *= scl[i];
            }
            const f32x4 scl4 = (f32x4){scl[0], scl[1], scl[2], scl[3]};
            #pragma unroll
            for (int vt = 0; vt < 8; ++vt) acc[vt] = acc[vt] * scl4;
        }
        float p0[4];
        #pragma unroll
        for (int i = 0; i < 4; ++i) {
            p0[i] = exp2f(sc0[i] - m2[i]);
            ll[i] += p0[i];                  // lane-local; reduced at epilogue
        }

        // ---- P -> bf16, per-wave LDS transpose, re-read as PV A-frag ----
        short* pw = &P_s[wave * 16 * PP];
        #pragma unroll
        for (int i = 0; i < 4; ++i)
            pw[(4 * g + i) * PP + lr] = (short)cvtpk(p0[i], p0[i]);
        asm volatile("s_waitcnt lgkmcnt(0)" ::: "memory");  // cross-lane RAW

        // A-frag: lane k-range = g*8..g*8+7; valid k only 0..15 -> lanes
        // g>=2 carry zeros (upper K-half of the mfma contributes nothing).
        FragAB pa;
        if (g < 2) {
            pa.d[0] = *(const uint2*)&pw[lr * PP + g * 8];
            pa.d[1] = *(const uint2*)&pw[lr * PP + g * 8 + 4];
        } else {
            pa.d[0] = make_uint2(0u, 0u);
            pa.d[1] = make_uint2(0u, 0u);
        }

        // ---- PV: wave's 128 v-cols, 8 mfma (upper K-half zero) ----
        __builtin_amdgcn_s_setprio(1);
        #pragma unroll
        for (int vt = 0; vt < 8; ++vt) {
            const int v = wave * 128 + vt * 16 + lr;
            FragAB vb;
            if (g < 2) {
                vb.d[0] = *(const uint2*)&V_s[v * VP + g * 8];
                vb.d[1] = *(const uint2*)&V_s[v * VP + g * 8 + 4];
            } else {
                vb.d[0] = make_uint2(0u, 0u);
                vb.d[1] = make_uint2(0u, 0u);
            }
            acc[vt] = __builtin_amdgcn_mfma_f32_16x16x32_bf16(pa.v, vb.v, acc[vt], 0, 0, 0);
        }
        __builtin_amdgcn_s_setprio(0);
    }

    // ---- epilogue: reduce lane-local l across the 16-lane dd-group ----
    #pragma unroll
    for (int i = 0; i < 4; ++i) {
        float s = ll[i];
        s += __shfl_xor(s, 1);
        s += __shfl_xor(s, 2);
        s += __shfl_xor(s, 4);
        s += __shfl_xor(s, 8);
        ll[i] = s;
    }

    // ---- write partials as BF16: h = 4g+i, v = wave*128 + vt*16 + lr ----
    unsigned short* ob = ws_o + (((size_t)b * nchunk + c) * NH) * DV;
    #pragma unroll
    for (int vt = 0; vt < 8; ++vt) {
        const int v = wave * 128 + vt * 16 + lr;
        #pragma unroll
        for (int i = 0; i < 4; ++i)
            ob[(4 * g + i) * DV + v] =
                (unsigned short)cvtpk(acc[vt][i], acc[vt][i]);
    }
    if (wave == 0 && lr == 0) {
        float* mlb = ws_ml + ((size_t)b * nchunk + c) * NH * 2;
        #pragma unroll
        for (int i = 0; i < 4; ++i) {
            mlb[(4 * g + i) * 2]     = m2[i];   // log2-domain running max
            mlb[(4 * g + i) * 2 + 1] = ll[i];
        }
    }
}

__global__ __launch_bounds__(256)
void mla_reduce(const int* __restrict__ lens,
                const unsigned short* __restrict__ ws_o,
                const float* __restrict__ ws_ml,
                float* __restrict__ out,
                int nchunk, int chunk)
{
    const int h = blockIdx.x;
    const int b = blockIdx.y;
    const int tid = (int)threadIdx.x;
    const int total = lens[b] + 1;
    const int nact = min(nchunk, (total + chunk - 1) / chunk);

    float M = NEGINF;
    {
        int c = 0;
        for (; c + 4 <= nact; c += 4) {       // 4 independent loads in flight
            const float m0 = ws_ml[(((size_t)b * nchunk + c    ) * NH + h) * 2];
            const float m1 = ws_ml[(((size_t)b * nchunk + c + 1) * NH + h) * 2];
            const float m2_ = ws_ml[(((size_t)b * nchunk + c + 2) * NH + h) * 2];
            const float m3 = ws_ml[(((size_t)b * nchunk + c + 3) * NH + h) * 2];
            M = fmaxf(M, fmaxf(fmaxf(m0, m1), fmaxf(m2_, m3)));
        }
        for (; c < nact; ++c)
            M = fmaxf(M, ws_ml[(((size_t)b * nchunk + c) * NH + h) * 2]);
    }

    float a0 = 0.f, a1 = 0.f, L = 0.f;
    {
        int c = 0;
        for (; c + 2 <= nact; c += 2) {       // 2 independent iterations
            const size_t mlb0 = (((size_t)b * nchunk + c    ) * NH + h) * 2;
            const size_t mlb1 = (((size_t)b * nchunk + c + 1) * NH + h) * 2;
            const float w0 = exp2f(ws_ml[mlb0] - M);
            const float w1 = exp2f(ws_ml[mlb1] - M);
            const uint32_t u0 = *(const uint32_t*)&ws_o[
                (((size_t)b * nchunk + c    ) * NH + h) * (size_t)DV + 2 * tid];
            const uint32_t u1 = *(const uint32_t*)&ws_o[
                (((size_t)b * nchunk + c + 1) * NH + h) * (size_t)DV + 2 * tid];
            const float o0x = __uint_as_float(u0 << 16);
            const float o0y = __uint_as_float(u0 & 0xFFFF0000u);
            const float o1x = __uint_as_float(u1 << 16);
            const float o1y = __uint_as_float(u1 & 0xFFFF0000u);
            L += w0 * ws_ml[mlb0 + 1] + w1 * ws_ml[mlb1 + 1];
            a0 = fmaf(w1, o1x, fmaf(w0, o0x, a0));
            a1 = fmaf(w1, o1y, fmaf(w0, o0y, a1));
        }
        for (; c < nact; ++c) {
            const size_t mlb = (((size_t)b * nchunk + c) * NH + h) * 2;
            const float w = exp2f(ws_ml[mlb] - M);
            L += w * ws_ml[mlb + 1];
            const uint32_t u = *(const uint32_t*)&ws_o[
                (((size_t)b * nchunk + c) * NH + h) * (size_t)DV + 2 * tid];
            a0 = fmaf(w, __uint_as_float(u << 16), a0);
            a1 = fmaf(w, __uint_as_float(u & 0xFFFF0000u), a1);
        }
    }
    const float inv = 1.f / L;
    *(float2*)&out[((size_t)b * NH + h) * (size_t)DV + 2 * tid] =
        make_float2(a0 * inv, a1 * inv);
}

extern "C" void kernel_launch(void* const* d_in, const int* in_sizes, int n_in,
                              void* d_out, int out_size, void* d_ws, size_t ws_size,
                              hipStream_t stream)
{
    (void)in_sizes; (void)n_in; (void)out_size;
    const float* qg    = (const float*)d_in[0];   // [B,H,576]
    const float* kvnew = (const float*)d_in[1];   // [B,1,576]
    const float* cache = (const float*)d_in[2];   // [B,4096,576]
    const int*   lens  = (const int*)d_in[3];     // [B]
    float* out = (float*)d_out;                   // [B,H,512] fp32

    // nchunk=16 (chunk=256); ws: bf16 ws_o (17 MB) + fp32 ws_ml
    int nchunk = 16;
    while (nchunk > 1 &&
           (size_t)NB * nchunk * NH * DV * 2 +
           (size_t)NB * nchunk * NH * 2 * sizeof(float) > ws_size)
        nchunk >>= 1;
    const int chunk = MAXLEN / nchunk;            // multiple of TR

    unsigned short* ws_o = (unsigned short*)d_ws;
    float* ws_ml = (float*)(ws_o + (size_t)NB * nchunk * NH * DV);

    dim3 gA(nchunk, NB);
    mla_mfma<<<gA, 256, 0, stream>>>(qg, kvnew, cache, lens, ws_o, ws_ml,
                                     nchunk, chunk);
    dim3 gB(NH, NB);
    mla_reduce<<<gB, 256, 0, stream>>>(lens, ws_o, ws_ml, out, nchunk, chunk);
}

// Round 19
// 117.787 us; speedup vs baseline: 1.6601x; 1.6601x over previous
//
#include <hip/hip_runtime.h>
#include <math.h>

// MLA decode attention, flash-decoding split + bf16 MFMA core.
// B=64, H=16, latent D=576, V=512, MAX_LEN=4096. fp32 in/out.
//
// R19 = EXACT REVERT to R15 (117.8us, session best). R18's TR=16 slim-tile
// regressed to 195us: halving the tile doubled round count while per-round
// fixed costs (barriers, softmax, P-transpose, 18 score MFMAs) stayed --
// per-row cost ~doubled. Occupancy lever is structurally closed: the dual
// K_s+Vt layout (required for cheap PV, per R14's u16-conflict failure)
// cannot fit 3 blocks/CU at TR=32.
//
// Final structure: grid (nchunk=16, B=64), 256 thr (4 waves), TR=32 rounds.
//  - Half-split register prefetch (A early / B late) -> cvtpk -> dual-write
//    K_s[32][584] row-major + Vt[512][36] transposed (bf16).
//  - 4-wave redundant scores: 2x18 mfma_f32_16x16x32_bf16, Q-frags
//    preloaded with scale*log2e folded.
//  - Log2-domain online softmax: skip-rescale (__any-gated), deferred
//    l-reduction to epilogue.
//  - P -> bf16 via per-wave LDS transpose; PV = 8 mfma/wave over private
//    128 v-cols from Vt (wide b64 reads).
//  - setprio(1) on MFMA clusters; OOB row clamp; LDS 79360 B (2 blk/CU).
//  - mla_reduce: flash-decoding merge, 4x/2x unrolled passes.

typedef __attribute__((ext_vector_type(8))) short bf16x8;
typedef __attribute__((ext_vector_type(4))) float f32x4;

namespace {
constexpr int NB = 64, NH = 16, MAXLEN = 4096, D = 576, DV = 512;
constexpr int KP = 584;   // K_s row stride (bf16): 1168 B rows, 16B-aligned
constexpr int VP = 36;    // Vt row stride (bf16): 72 B rows, 8B-aligned
constexpr int PP = 40;    // P_s row stride (bf16)
constexpr float SCALE_LOG2E = 0.041666666666666664f * 1.4426950408889634f;
constexpr float NEGINF = -1e30f;
}

__device__ __forceinline__ uint32_t cvtpk(float a, float b) {
    uint32_t r;
    asm("v_cvt_pk_bf16_f32 %0, %1, %2" : "=v"(r) : "v"(a), "v"(b));
    return r;   // low16 = bf16(a), high16 = bf16(b)
}

union FragAB { bf16x8 v; uint32_t u[4]; };

__global__ __launch_bounds__(256, 2)
void mla_mfma(const float* __restrict__ qg, const float* __restrict__ kvnew,
              const float* __restrict__ cache, const int* __restrict__ lens,
              float* __restrict__ ws_o, float* __restrict__ ws_ml,
              int nchunk, int chunk)
{
    const int c = blockIdx.x, b = blockIdx.y;
    const int total = lens[b] + 1;
    const int start = c * chunk;
    if (start >= total) return;               // uniform, before any barrier
    const int end = min(start + chunk, total);
    const int newpos = total - 1;

    __shared__ short K_s[32 * KP];            // 37376 B row-major bf16
    __shared__ short V_s[DV * VP];            // 36864 B Vt[v][r] bf16
    __shared__ short P_s[4 * 16 * PP];        //  5120 B   (total 79360)

    const int tid  = (int)threadIdx.x;
    const int wave = tid >> 6, lane = tid & 63;
    const int lr = lane & 15, g = lane >> 4;

    const float* vnew = kvnew + (size_t)b * D;
    const float* cb   = cache + (size_t)b * MAXLEN * D;

    const int rg = tid >> 5;                  // staging row-group: rows rg*4+i
    const int cl = tid & 31;                  // staging col-lane

    float4 nxA[2][4];                         // early half (cols f4 0..63)
    float4 nxB[3][4];                         // late half (cols f4 64..143)

#define ROWPTRS(R0N)                                                           \
        const int gr0 = (R0N) + rg * 4;                                        \
        const int r0c = min(gr0,     MAXLEN - 1);                              \
        const int r1c = min(gr0 + 1, MAXLEN - 1);                              \
        const int r2c = min(gr0 + 2, MAXLEN - 1);                              \
        const int r3c = min(gr0 + 3, MAXLEN - 1);                              \
        const float* s0 = (gr0     == newpos) ? vnew : (cb + (size_t)r0c * D); \
        const float* s1 = (gr0 + 1 == newpos) ? vnew : (cb + (size_t)r1c * D); \
        const float* s2 = (gr0 + 2 == newpos) ? vnew : (cb + (size_t)r2c * D); \
        const float* s3 = (gr0 + 3 == newpos) ? vnew : (cb + (size_t)r3c * D);

#define STAGE_LOAD_A(R0N)                                                      \
    {                                                                          \
        ROWPTRS(R0N)                                                           \
        _Pragma("unroll")                                                      \
        for (int it = 0; it < 2; ++it) {                                       \
            const int cf = 32 * it + cl;                                       \
            nxA[it][0] = *(const float4*)(s0 + cf * 4);                        \
            nxA[it][1] = *(const float4*)(s1 + cf * 4);                        \
            nxA[it][2] = *(const float4*)(s2 + cf * 4);                        \
            nxA[it][3] = *(const float4*)(s3 + cf * 4);                        \
        }                                                                      \
    }

#define STAGE_LOAD_B(R0N)                                                      \
    {                                                                          \
        ROWPTRS(R0N)                                                           \
        _Pragma("unroll")                                                      \
        for (int jt = 0; jt < 3; ++jt) {                                       \
            const int cf = 32 * (jt + 2) + cl;                                 \
            if (cf < 144) {                                                    \
                nxB[jt][0] = *(const float4*)(s0 + cf * 4);                    \
                nxB[jt][1] = *(const float4*)(s1 + cf * 4);                    \
                nxB[jt][2] = *(const float4*)(s2 + cf * 4);                    \
                nxB[jt][3] = *(const float4*)(s3 + cf * 4);                    \
            }                                                                  \
        }                                                                      \
    }

#define WRITE_ONE(NX, CF)                                                      \
    {                                                                          \
        uint2 w;                                                               \
        w.x = cvtpk(NX[0].x, NX[0].y); w.y = cvtpk(NX[0].z, NX[0].w);          \
        *(uint2*)&K_s[(rg * 4 + 0) * KP + (CF) * 4] = w;                       \
        w.x = cvtpk(NX[1].x, NX[1].y); w.y = cvtpk(NX[1].z, NX[1].w);          \
        *(uint2*)&K_s[(rg * 4 + 1) * KP + (CF) * 4] = w;                       \
        w.x = cvtpk(NX[2].x, NX[2].y); w.y = cvtpk(NX[2].z, NX[2].w);          \
        *(uint2*)&K_s[(rg * 4 + 2) * KP + (CF) * 4] = w;                       \
        w.x = cvtpk(NX[3].x, NX[3].y); w.y = cvtpk(NX[3].z, NX[3].w);          \
        *(uint2*)&K_s[(rg * 4 + 3) * KP + (CF) * 4] = w;                       \
        if ((CF) < 128) {                                                      \
            const int v0 = (CF) * 4;                                           \
            w.x = cvtpk(NX[0].x, NX[1].x); w.y = cvtpk(NX[2].x, NX[3].x);      \
            *(uint2*)&V_s[(v0 + 0) * VP + rg * 4] = w;                         \
            w.x = cvtpk(NX[0].y, NX[1].y); w.y = cvtpk(NX[2].y, NX[3].y);      \
            *(uint2*)&V_s[(v0 + 1) * VP + rg * 4] = w;                         \
            w.x = cvtpk(NX[0].z, NX[1].z); w.y = cvtpk(NX[2].z, NX[3].z);      \
            *(uint2*)&V_s[(v0 + 2) * VP + rg * 4] = w;                         \
            w.x = cvtpk(NX[0].w, NX[1].w); w.y = cvtpk(NX[2].w, NX[3].w);      \
            *(uint2*)&V_s[(v0 + 3) * VP + rg * 4] = w;                         \
        }                                                                      \
    }

#define STAGE_WRITE_A()                                                        \
    {                                                                          \
        _Pragma("unroll")                                                      \
        for (int it = 0; it < 2; ++it) {                                       \
            const int cf = 32 * it + cl;                                       \
            WRITE_ONE(nxA[it], cf)                                             \
        }                                                                      \
    }

#define STAGE_WRITE_B()                                                        \
    {                                                                          \
        _Pragma("unroll")                                                      \
        for (int jt = 0; jt < 3; ++jt) {                                       \
            const int cf = 32 * (jt + 2) + cl;                                 \
            if (cf < 144) { WRITE_ONE(nxB[jt], cf) }                           \
        }                                                                      \
    }

    // ---- Q A-frags: lane holds Q[h=lr][kc*32 + g*8 + j], scale folded ----
    FragAB qf[18];
    {
        const float* qrow = qg + ((size_t)b * NH + lr) * D + g * 8;
        #pragma unroll
        for (int kc = 0; kc < 18; ++kc) {
            float4 x = *(const float4*)(qrow + kc * 32);
            float4 y = *(const float4*)(qrow + kc * 32 + 4);
            qf[kc].u[0] = cvtpk(x.x * SCALE_LOG2E, x.y * SCALE_LOG2E);
            qf[kc].u[1] = cvtpk(x.z * SCALE_LOG2E, x.w * SCALE_LOG2E);
            qf[kc].u[2] = cvtpk(y.x * SCALE_LOG2E, y.y * SCALE_LOG2E);
            qf[kc].u[3] = cvtpk(y.z * SCALE_LOG2E, y.w * SCALE_LOG2E);
        }
    }

    f32x4 acc[8];
    #pragma unroll
    for (int i = 0; i < 8; ++i) acc[i] = (f32x4){0.f, 0.f, 0.f, 0.f};
    float m2[4] = {NEGINF, NEGINF, NEGINF, NEGINF};
    float ll[4] = {0.f, 0.f, 0.f, 0.f};      // lane-local partial sums

    // ---- prologue: stage tile 0 ----
    STAGE_LOAD_A(start);
    STAGE_LOAD_B(start);
    STAGE_WRITE_A();
    STAGE_WRITE_B();
    __syncthreads();

    for (int r0 = start; r0 < end; r0 += 32) {
        const bool have_next = (r0 + 32 < end);     // block-uniform
        if (have_next) STAGE_LOAD_A(r0 + 32);       // early half in flight

        // ---- scores: S[16h, 32r], two 16x16 tiles ----
        f32x4 sc0 = (f32x4){0.f, 0.f, 0.f, 0.f};
        f32x4 sc1 = (f32x4){0.f, 0.f, 0.f, 0.f};
        __builtin_amdgcn_s_setprio(1);
        #pragma unroll
        for (int kc = 0; kc < 18; ++kc) {
            FragAB kb0, kb1;
            kb0.v = *(const bf16x8*)&K_s[lr * KP + kc * 32 + g * 8];
            kb1.v = *(const bf16x8*)&K_s[(16 + lr) * KP + kc * 32 + g * 8];
            sc0 = __builtin_amdgcn_mfma_f32_16x16x32_bf16(qf[kc].v, kb0.v, sc0, 0, 0, 0);
            sc1 = __builtin_amdgcn_mfma_f32_16x16x32_bf16(qf[kc].v, kb1.v, sc1, 0, 0, 0);
        }
        __builtin_amdgcn_s_setprio(0);
        // mask invalid rows (lane's D-col = row r0+lr / r0+16+lr)
        if (r0 + lr >= end)      sc0 = (f32x4){NEGINF, NEGINF, NEGINF, NEGINF};
        if (r0 + 16 + lr >= end) sc1 = (f32x4){NEGINF, NEGINF, NEGINF, NEGINF};

        // ---- online softmax (log2 domain), skip-rescale + deferred l ----
        float mt[4];
        int grew = 0;
        #pragma unroll
        for (int i = 0; i < 4; ++i) {
            float t = fmaxf(sc0[i], sc1[i]);
            t = fmaxf(t, __shfl_xor(t, 1));
            t = fmaxf(t, __shfl_xor(t, 2));
            t = fmaxf(t, __shfl_xor(t, 4));
            t = fmaxf(t, __shfl_xor(t, 8));
            mt[i] = t;
            grew |= (t > m2[i]) ? 1 : 0;
        }
        if (__any(grew)) {                   // wave-uniform branch
            float scl[4];
            #pragma unroll
            for (int i = 0; i < 4; ++i) {
                const float nm = fmaxf(m2[i], mt[i]);
                scl[i] = exp2f(m2[i] - nm);  // ==1 for non-growing groups
                m2[i] = nm;
                ll[i] *= scl[i];
            }
            const f32x4 scl4 = (f32x4){scl[0], scl[1], scl[2], scl[3]};
            #pragma unroll
            for (int vt = 0; vt < 8; ++vt) acc[vt] = acc[vt] * scl4;
        }
        float p0[4], p1[4];
        #pragma unroll
        for (int i = 0; i < 4; ++i) {
            p0[i] = exp2f(sc0[i] - m2[i]);
            p1[i] = exp2f(sc1[i] - m2[i]);
            ll[i] += p0[i] + p1[i];          // lane-local; reduced at epilogue
        }

        // ---- P -> bf16, per-wave LDS transpose, re-read as PV A-frag ----
        short* pw = &P_s[wave * 16 * PP];
        #pragma unroll
        for (int i = 0; i < 4; ++i) {
            pw[(4 * g + i) * PP + lr]      = (short)cvtpk(p0[i], p0[i]);
            pw[(4 * g + i) * PP + 16 + lr] = (short)cvtpk(p1[i], p1[i]);
        }
        asm volatile("s_waitcnt lgkmcnt(0)" ::: "memory");  // cross-lane RAW
        FragAB pa;
        pa.v = *(const bf16x8*)&pw[lr * PP + g * 8];

        // ---- PV: wave's 128 v-cols, 8 mfma ----
        __builtin_amdgcn_s_setprio(1);
        #pragma unroll
        for (int vt = 0; vt < 8; ++vt) {
            const int v = wave * 128 + vt * 16 + lr;
            FragAB vb;
            *(uint2*)&vb.u[0] = *(const uint2*)&V_s[v * VP + g * 8];
            *(uint2*)&vb.u[2] = *(const uint2*)&V_s[v * VP + g * 8 + 4];
            acc[vt] = __builtin_amdgcn_mfma_f32_16x16x32_bf16(pa.v, vb.v, acc[vt], 0, 0, 0);
        }
        __builtin_amdgcn_s_setprio(0);

        if (have_next) STAGE_LOAD_B(r0 + 32);   // late half issued pre-barrier
        __syncthreads();                        // all waves done reading LDS
        if (have_next) { STAGE_WRITE_A(); STAGE_WRITE_B(); }
        __syncthreads();                        // next round staged
    }

    // ---- epilogue: reduce lane-local l across the 16-lane dd-group ----
    #pragma unroll
    for (int i = 0; i < 4; ++i) {
        float s = ll[i];
        s += __shfl_xor(s, 1);
        s += __shfl_xor(s, 2);
        s += __shfl_xor(s, 4);
        s += __shfl_xor(s, 8);
        ll[i] = s;
    }

    // ---- write partials: lane covers h = 4g+i, v = wave*128 + vt*16 + lr --
    float* ob = ws_o + (((size_t)b * nchunk + c) * NH) * DV;
    #pragma unroll
    for (int vt = 0; vt < 8; ++vt) {
        const int v = wave * 128 + vt * 16 + lr;
        #pragma unroll
        for (int i = 0; i < 4; ++i)
            ob[(4 * g + i) * DV + v] = acc[vt][i];
    }
    if (wave == 0 && lr == 0) {
        float* mlb = ws_ml + ((size_t)b * nchunk + c) * NH * 2;
        #pragma unroll
        for (int i = 0; i < 4; ++i) {
            mlb[(4 * g + i) * 2]     = m2[i];   // log2-domain running max
            mlb[(4 * g + i) * 2 + 1] = ll[i];
        }
    }
#undef STAGE_LOAD_A
#undef STAGE_LOAD_B
#undef STAGE_WRITE_A
#undef STAGE_WRITE_B
#undef WRITE_ONE
#undef ROWPTRS
}

__global__ __launch_bounds__(256)
void mla_reduce(const int* __restrict__ lens,
                const float* __restrict__ ws_o,
                const float* __restrict__ ws_ml,
                float* __restrict__ out,
                int nchunk, int chunk)
{
    const int h = blockIdx.x;
    const int b = blockIdx.y;
    const int tid = (int)threadIdx.x;
    const int total = lens[b] + 1;
    const int nact = min(nchunk, (total + chunk - 1) / chunk);

    float M = NEGINF;
    {
        int c = 0;
        for (; c + 4 <= nact; c += 4) {       // 4 independent loads in flight
            const float m0 = ws_ml[(((size_t)b * nchunk + c    ) * NH + h) * 2];
            const float m1 = ws_ml[(((size_t)b * nchunk + c + 1) * NH + h) * 2];
            const float m2_ = ws_ml[(((size_t)b * nchunk + c + 2) * NH + h) * 2];
            const float m3 = ws_ml[(((size_t)b * nchunk + c + 3) * NH + h) * 2];
            M = fmaxf(M, fmaxf(fmaxf(m0, m1), fmaxf(m2_, m3)));
        }
        for (; c < nact; ++c)
            M = fmaxf(M, ws_ml[(((size_t)b * nchunk + c) * NH + h) * 2]);
    }

    float a0 = 0.f, a1 = 0.f, L = 0.f;
    {
        int c = 0;
        for (; c + 2 <= nact; c += 2) {       // 2 independent iterations
            const size_t mlb0 = (((size_t)b * nchunk + c    ) * NH + h) * 2;
            const size_t mlb1 = (((size_t)b * nchunk + c + 1) * NH + h) * 2;
            const float w0 = exp2f(ws_ml[mlb0] - M);
            const float w1 = exp2f(ws_ml[mlb1] - M);
            const float2 o0 = *(const float2*)&ws_o[
                (((size_t)b * nchunk + c    ) * NH + h) * (size_t)DV + 2 * tid];
            const float2 o1 = *(const float2*)&ws_o[
                (((size_t)b * nchunk + c + 1) * NH + h) * (size_t)DV + 2 * tid];
            L += w0 * ws_ml[mlb0 + 1] + w1 * ws_ml[mlb1 + 1];
            a0 = fmaf(w1, o1.x, fmaf(w0, o0.x, a0));
            a1 = fmaf(w1, o1.y, fmaf(w0, o0.y, a1));
        }
        for (; c < nact; ++c) {
            const size_t mlb = (((size_t)b * nchunk + c) * NH + h) * 2;
            const float w = exp2f(ws_ml[mlb] - M);
            L += w * ws_ml[mlb + 1];
            const float2 o = *(const float2*)&ws_o[
                (((size_t)b * nchunk + c) * NH + h) * (size_t)DV + 2 * tid];
            a0 = fmaf(w, o.x, a0);
            a1 = fmaf(w, o.y, a1);
        }
    }
    const float inv = 1.f / L;
    *(float2*)&out[((size_t)b * NH + h) * (size_t)DV + 2 * tid] =
        make_float2(a0 * inv, a1 * inv);
}

extern "C" void kernel_launch(void* const* d_in, const int* in_sizes, int n_in,
                              void* d_out, int out_size, void* d_ws, size_t ws_size,
                              hipStream_t stream)
{
    (void)in_sizes; (void)n_in; (void)out_size;
    const float* qg    = (const float*)d_in[0];   // [B,H,576]
    const float* kvnew = (const float*)d_in[1];   // [B,1,576]
    const float* cache = (const float*)d_in[2];   // [B,4096,576]
    const int*   lens  = (const int*)d_in[3];     // [B]
    float* out = (float*)d_out;                   // [B,H,512] fp32

    // nchunk=16 (chunk=256) — halves ws traffic + reduce loop depth vs 32.
    int nchunk = 16;
    while (nchunk > 1 &&
           (size_t)NB * nchunk * NH * (DV + 2) * sizeof(float) > ws_size)
        nchunk >>= 1;
    const int chunk = MAXLEN / nchunk;            // multiple of 32

    float* ws_o  = (float*)d_ws;
    float* ws_ml = ws_o + (size_t)NB * nchunk * NH * DV;

    dim3 gA(nchunk, NB);
    mla_mfma<<<gA, 256, 0, stream>>>(qg, kvnew, cache, lens, ws_o, ws_ml,
                                     nchunk, chunk);
    dim3 gB(NH, NB);
    mla_reduce<<<gB, 256, 0, stream>>>(lens, ws_o, ws_ml, out, nchunk, chunk);
}

// Round 20
// 116.057 us; speedup vs baseline: 1.6848x; 1.0149x over previous
//
#include <hip/hip_runtime.h>
#include <math.h>

// MLA decode attention, flash-decoding split + bf16 MFMA core.
// B=64, H=16, latent D=576, V=512, MAX_LEN=4096. fp32 in/out.
//
// R20 = R19/R15 (117.8us, session best, twice-reproduced) + true defer-max
// (T13, THR=8 log2-units) in the rescale gate: the acc-rescale block now
// fires only when a tile max exceeds the running max by >8 (essentially
// never after round 1; score std ~1.4 log2-units). p bounded by 2^8, ll by
// 2^16 -- exact fp32 path, normalization semantics unchanged (reduce merges
// on the stored m2 exactly as before).
//
// Structure (locked after 20 rounds of ablation):
//  - grid (nchunk=16, B=64), 256 thr (4 waves), TR=32 rounds/chunk.
//  - Half-split register prefetch (A early / B late) -> cvtpk -> dual-write
//    K_s[32][584] row-major + Vt[512][36] transposed (bf16).
//  - 4-wave redundant scores: 2x18 mfma_f32_16x16x32_bf16, Q-frags
//    preloaded with scale*log2e folded. (Redundancy is free: falsified
//    alternatives -- kc-split, slim tiles, u16-PV -- all regressed.)
//  - Log2-domain online softmax: defer-max rescale, deferred l-reduction.
//  - P -> bf16 via per-wave LDS transpose; PV = 8 mfma/wave over private
//    128 v-cols from Vt (wide b64 reads).
//  - setprio(1) on MFMA clusters; OOB row clamp; LDS 79360 B (2 blk/CU).
//  - mla_reduce: flash-decoding merge, 4x/2x unrolled passes.

typedef __attribute__((ext_vector_type(8))) short bf16x8;
typedef __attribute__((ext_vector_type(4))) float f32x4;

namespace {
constexpr int NB = 64, NH = 16, MAXLEN = 4096, D = 576, DV = 512;
constexpr int KP = 584;   // K_s row stride (bf16): 1168 B rows, 16B-aligned
constexpr int VP = 36;    // Vt row stride (bf16): 72 B rows, 8B-aligned
constexpr int PP = 40;    // P_s row stride (bf16)
constexpr float SCALE_LOG2E = 0.041666666666666664f * 1.4426950408889634f;
constexpr float NEGINF = -1e30f;
constexpr float THR2 = 8.0f;  // defer-max threshold (log2 domain)
}

__device__ __forceinline__ uint32_t cvtpk(float a, float b) {
    uint32_t r;
    asm("v_cvt_pk_bf16_f32 %0, %1, %2" : "=v"(r) : "v"(a), "v"(b));
    return r;   // low16 = bf16(a), high16 = bf16(b)
}

union FragAB { bf16x8 v; uint32_t u[4]; };

__global__ __launch_bounds__(256, 2)
void mla_mfma(const float* __restrict__ qg, const float* __restrict__ kvnew,
              const float* __restrict__ cache, const int* __restrict__ lens,
              float* __restrict__ ws_o, float* __restrict__ ws_ml,
              int nchunk, int chunk)
{
    const int c = blockIdx.x, b = blockIdx.y;
    const int total = lens[b] + 1;
    const int start = c * chunk;
    if (start >= total) return;               // uniform, before any barrier
    const int end = min(start + chunk, total);
    const int newpos = total - 1;

    __shared__ short K_s[32 * KP];            // 37376 B row-major bf16
    __shared__ short V_s[DV * VP];            // 36864 B Vt[v][r] bf16
    __shared__ short P_s[4 * 16 * PP];        //  5120 B   (total 79360)

    const int tid  = (int)threadIdx.x;
    const int wave = tid >> 6, lane = tid & 63;
    const int lr = lane & 15, g = lane >> 4;

    const float* vnew = kvnew + (size_t)b * D;
    const float* cb   = cache + (size_t)b * MAXLEN * D;

    const int rg = tid >> 5;                  // staging row-group: rows rg*4+i
    const int cl = tid & 31;                  // staging col-lane

    float4 nxA[2][4];                         // early half (cols f4 0..63)
    float4 nxB[3][4];                         // late half (cols f4 64..143)

#define ROWPTRS(R0N)                                                           \
        const int gr0 = (R0N) + rg * 4;                                        \
        const int r0c = min(gr0,     MAXLEN - 1);                              \
        const int r1c = min(gr0 + 1, MAXLEN - 1);                              \
        const int r2c = min(gr0 + 2, MAXLEN - 1);                              \
        const int r3c = min(gr0 + 3, MAXLEN - 1);                              \
        const float* s0 = (gr0     == newpos) ? vnew : (cb + (size_t)r0c * D); \
        const float* s1 = (gr0 + 1 == newpos) ? vnew : (cb + (size_t)r1c * D); \
        const float* s2 = (gr0 + 2 == newpos) ? vnew : (cb + (size_t)r2c * D); \
        const float* s3 = (gr0 + 3 == newpos) ? vnew : (cb + (size_t)r3c * D);

#define STAGE_LOAD_A(R0N)                                                      \
    {                                                                          \
        ROWPTRS(R0N)                                                           \
        _Pragma("unroll")                                                      \
        for (int it = 0; it < 2; ++it) {                                       \
            const int cf = 32 * it + cl;                                       \
            nxA[it][0] = *(const float4*)(s0 + cf * 4);                        \
            nxA[it][1] = *(const float4*)(s1 + cf * 4);                        \
            nxA[it][2] = *(const float4*)(s2 + cf * 4);                        \
            nxA[it][3] = *(const float4*)(s3 + cf * 4);                        \
        }                                                                      \
    }

#define STAGE_LOAD_B(R0N)                                                      \
    {                                                                          \
        ROWPTRS(R0N)                                                           \
        _Pragma("unroll")                                                      \
        for (int jt = 0; jt < 3; ++jt) {                                       \
            const int cf = 32 * (jt + 2) + cl;                                 \
            if (cf < 144) {                                                    \
                nxB[jt][0] = *(const float4*)(s0 + cf * 4);                    \
                nxB[jt][1] = *(const float4*)(s1 + cf * 4);                    \
                nxB[jt][2] = *(const float4*)(s2 + cf * 4);                    \
                nxB[jt][3] = *(const float4*)(s3 + cf * 4);                    \
            }                                                                  \
        }                                                                      \
    }

#define WRITE_ONE(NX, CF)                                                      \
    {                                                                          \
        uint2 w;                                                               \
        w.x = cvtpk(NX[0].x, NX[0].y); w.y = cvtpk(NX[0].z, NX[0].w);          \
        *(uint2*)&K_s[(rg * 4 + 0) * KP + (CF) * 4] = w;                       \
        w.x = cvtpk(NX[1].x, NX[1].y); w.y = cvtpk(NX[1].z, NX[1].w);          \
        *(uint2*)&K_s[(rg * 4 + 1) * KP + (CF) * 4] = w;                       \
        w.x = cvtpk(NX[2].x, NX[2].y); w.y = cvtpk(NX[2].z, NX[2].w);          \
        *(uint2*)&K_s[(rg * 4 + 2) * KP + (CF) * 4] = w;                       \
        w.x = cvtpk(NX[3].x, NX[3].y); w.y = cvtpk(NX[3].z, NX[3].w);          \
        *(uint2*)&K_s[(rg * 4 + 3) * KP + (CF) * 4] = w;                       \
        if ((CF) < 128) {                                                      \
            const int v0 = (CF) * 4;                                           \
            w.x = cvtpk(NX[0].x, NX[1].x); w.y = cvtpk(NX[2].x, NX[3].x);      \
            *(uint2*)&V_s[(v0 + 0) * VP + rg * 4] = w;                         \
            w.x = cvtpk(NX[0].y, NX[1].y); w.y = cvtpk(NX[2].y, NX[3].y);      \
            *(uint2*)&V_s[(v0 + 1) * VP + rg * 4] = w;                         \
            w.x = cvtpk(NX[0].z, NX[1].z); w.y = cvtpk(NX[2].z, NX[3].z);      \
            *(uint2*)&V_s[(v0 + 2) * VP + rg * 4] = w;                         \
            w.x = cvtpk(NX[0].w, NX[1].w); w.y = cvtpk(NX[2].w, NX[3].w);      \
            *(uint2*)&V_s[(v0 + 3) * VP + rg * 4] = w;                         \
        }                                                                      \
    }

#define STAGE_WRITE_A()                                                        \
    {                                                                          \
        _Pragma("unroll")                                                      \
        for (int it = 0; it < 2; ++it) {                                       \
            const int cf = 32 * it + cl;                                       \
            WRITE_ONE(nxA[it], cf)                                             \
        }                                                                      \
    }

#define STAGE_WRITE_B()                                                        \
    {                                                                          \
        _Pragma("unroll")                                                      \
        for (int jt = 0; jt < 3; ++jt) {                                       \
            const int cf = 32 * (jt + 2) + cl;                                 \
            if (cf < 144) { WRITE_ONE(nxB[jt], cf) }                           \
        }                                                                      \
    }

    // ---- Q A-frags: lane holds Q[h=lr][kc*32 + g*8 + j], scale folded ----
    FragAB qf[18];
    {
        const float* qrow = qg + ((size_t)b * NH + lr) * D + g * 8;
        #pragma unroll
        for (int kc = 0; kc < 18; ++kc) {
            float4 x = *(const float4*)(qrow + kc * 32);
            float4 y = *(const float4*)(qrow + kc * 32 + 4);
            qf[kc].u[0] = cvtpk(x.x * SCALE_LOG2E, x.y * SCALE_LOG2E);
            qf[kc].u[1] = cvtpk(x.z * SCALE_LOG2E, x.w * SCALE_LOG2E);
            qf[kc].u[2] = cvtpk(y.x * SCALE_LOG2E, y.y * SCALE_LOG2E);
            qf[kc].u[3] = cvtpk(y.z * SCALE_LOG2E, y.w * SCALE_LOG2E);
        }
    }

    f32x4 acc[8];
    #pragma unroll
    for (int i = 0; i < 8; ++i) acc[i] = (f32x4){0.f, 0.f, 0.f, 0.f};
    float m2[4] = {NEGINF, NEGINF, NEGINF, NEGINF};
    float ll[4] = {0.f, 0.f, 0.f, 0.f};      // lane-local partial sums

    // ---- prologue: stage tile 0 ----
    STAGE_LOAD_A(start);
    STAGE_LOAD_B(start);
    STAGE_WRITE_A();
    STAGE_WRITE_B();
    __syncthreads();

    for (int r0 = start; r0 < end; r0 += 32) {
        const bool have_next = (r0 + 32 < end);     // block-uniform
        if (have_next) STAGE_LOAD_A(r0 + 32);       // early half in flight

        // ---- scores: S[16h, 32r], two 16x16 tiles ----
        f32x4 sc0 = (f32x4){0.f, 0.f, 0.f, 0.f};
        f32x4 sc1 = (f32x4){0.f, 0.f, 0.f, 0.f};
        __builtin_amdgcn_s_setprio(1);
        #pragma unroll
        for (int kc = 0; kc < 18; ++kc) {
            FragAB kb0, kb1;
            kb0.v = *(const bf16x8*)&K_s[lr * KP + kc * 32 + g * 8];
            kb1.v = *(const bf16x8*)&K_s[(16 + lr) * KP + kc * 32 + g * 8];
            sc0 = __builtin_amdgcn_mfma_f32_16x16x32_bf16(qf[kc].v, kb0.v, sc0, 0, 0, 0);
            sc1 = __builtin_amdgcn_mfma_f32_16x16x32_bf16(qf[kc].v, kb1.v, sc1, 0, 0, 0);
        }
        __builtin_amdgcn_s_setprio(0);
        // mask invalid rows (lane's D-col = row r0+lr / r0+16+lr)
        if (r0 + lr >= end)      sc0 = (f32x4){NEGINF, NEGINF, NEGINF, NEGINF};
        if (r0 + 16 + lr >= end) sc1 = (f32x4){NEGINF, NEGINF, NEGINF, NEGINF};

        // ---- online softmax (log2 domain): defer-max + deferred l ----
        float mt[4];
        int grew = 0;
        #pragma unroll
        for (int i = 0; i < 4; ++i) {
            float t = fmaxf(sc0[i], sc1[i]);
            t = fmaxf(t, __shfl_xor(t, 1));
            t = fmaxf(t, __shfl_xor(t, 2));
            t = fmaxf(t, __shfl_xor(t, 4));
            t = fmaxf(t, __shfl_xor(t, 8));
            mt[i] = t;
            grew |= (t > m2[i] + THR2) ? 1 : 0;   // defer: tolerate +8 log2
        }
        if (__any(grew)) {                   // wave-uniform, now RARE
            float scl[4];
            #pragma unroll
            for (int i = 0; i < 4; ++i) {
                const float nm = fmaxf(m2[i], mt[i]);
                scl[i] = exp2f(m2[i] - nm);  // ==1 for non-growing groups
                m2[i] = nm;
                ll[i] *= scl[i];
            }
            const f32x4 scl4 = (f32x4){scl[0], scl[1], scl[2], scl[3]};
            #pragma unroll
            for (int vt = 0; vt < 8; ++vt) acc[vt] = acc[vt] * scl4;
        }
        float p0[4], p1[4];
        #pragma unroll
        for (int i = 0; i < 4; ++i) {
            p0[i] = exp2f(sc0[i] - m2[i]);   // bounded by 2^THR2
            p1[i] = exp2f(sc1[i] - m2[i]);
            ll[i] += p0[i] + p1[i];          // lane-local; reduced at epilogue
        }

        // ---- P -> bf16, per-wave LDS transpose, re-read as PV A-frag ----
        short* pw = &P_s[wave * 16 * PP];
        #pragma unroll
        for (int i = 0; i < 4; ++i) {
            pw[(4 * g + i) * PP + lr]      = (short)cvtpk(p0[i], p0[i]);
            pw[(4 * g + i) * PP + 16 + lr] = (short)cvtpk(p1[i], p1[i]);
        }
        asm volatile("s_waitcnt lgkmcnt(0)" ::: "memory");  // cross-lane RAW
        FragAB pa;
        pa.v = *(const bf16x8*)&pw[lr * PP + g * 8];

        // ---- PV: wave's 128 v-cols, 8 mfma ----
        __builtin_amdgcn_s_setprio(1);
        #pragma unroll
        for (int vt = 0; vt < 8; ++vt) {
            const int v = wave * 128 + vt * 16 + lr;
            FragAB vb;
            *(uint2*)&vb.u[0] = *(const uint2*)&V_s[v * VP + g * 8];
            *(uint2*)&vb.u[2] = *(const uint2*)&V_s[v * VP + g * 8 + 4];
            acc[vt] = __builtin_amdgcn_mfma_f32_16x16x32_bf16(pa.v, vb.v, acc[vt], 0, 0, 0);
        }
        __builtin_amdgcn_s_setprio(0);

        if (have_next) STAGE_LOAD_B(r0 + 32);   // late half issued pre-barrier
        __syncthreads();                        // all waves done reading LDS
        if (have_next) { STAGE_WRITE_A(); STAGE_WRITE_B(); }
        __syncthreads();                        // next round staged
    }

    // ---- epilogue: reduce lane-local l across the 16-lane dd-group ----
    #pragma unroll
    for (int i = 0; i < 4; ++i) {
        float s = ll[i];
        s += __shfl_xor(s, 1);
        s += __shfl_xor(s, 2);
        s += __shfl_xor(s, 4);
        s += __shfl_xor(s, 8);
        ll[i] = s;
    }

    // ---- write partials: lane covers h = 4g+i, v = wave*128 + vt*16 + lr --
    float* ob = ws_o + (((size_t)b * nchunk + c) * NH) * DV;
    #pragma unroll
    for (int vt = 0; vt < 8; ++vt) {
        const int v = wave * 128 + vt * 16 + lr;
        #pragma unroll
        for (int i = 0; i < 4; ++i)
            ob[(4 * g + i) * DV + v] = acc[vt][i];
    }
    if (wave == 0 && lr == 0) {
        float* mlb = ws_ml + ((size_t)b * nchunk + c) * NH * 2;
        #pragma unroll
        for (int i = 0; i < 4; ++i) {
            mlb[(4 * g + i) * 2]     = m2[i];   // log2-domain running max
            mlb[(4 * g + i) * 2 + 1] = ll[i];
        }
    }
#undef STAGE_LOAD_A
#undef STAGE_LOAD_B
#undef STAGE_WRITE_A
#undef STAGE_WRITE_B
#undef WRITE_ONE
#undef ROWPTRS
}

__global__ __launch_bounds__(256)
void mla_reduce(const int* __restrict__ lens,
                const float* __restrict__ ws_o,
                const float* __restrict__ ws_ml,
                float* __restrict__ out,
                int nchunk, int chunk)
{
    const int h = blockIdx.x;
    const int b = blockIdx.y;
    const int tid = (int)threadIdx.x;
    const int total = lens[b] + 1;
    const int nact = min(nchunk, (total + chunk - 1) / chunk);

    float M = NEGINF;
    {
        int c = 0;
        for (; c + 4 <= nact; c += 4) {       // 4 independent loads in flight
            const float m0 = ws_ml[(((size_t)b * nchunk + c    ) * NH + h) * 2];
            const float m1 = ws_ml[(((size_t)b * nchunk + c + 1) * NH + h) * 2];
            const float m2_ = ws_ml[(((size_t)b * nchunk + c + 2) * NH + h) * 2];
            const float m3 = ws_ml[(((size_t)b * nchunk + c + 3) * NH + h) * 2];
            M = fmaxf(M, fmaxf(fmaxf(m0, m1), fmaxf(m2_, m3)));
        }
        for (; c < nact; ++c)
            M = fmaxf(M, ws_ml[(((size_t)b * nchunk + c) * NH + h) * 2]);
    }

    float a0 = 0.f, a1 = 0.f, L = 0.f;
    {
        int c = 0;
        for (; c + 2 <= nact; c += 2) {       // 2 independent iterations
            const size_t mlb0 = (((size_t)b * nchunk + c    ) * NH + h) * 2;
            const size_t mlb1 = (((size_t)b * nchunk + c + 1) * NH + h) * 2;
            const float w0 = exp2f(ws_ml[mlb0] - M);
            const float w1 = exp2f(ws_ml[mlb1] - M);
            const float2 o0 = *(const float2*)&ws_o[
                (((size_t)b * nchunk + c    ) * NH + h) * (size_t)DV + 2 * tid];
            const float2 o1 = *(const float2*)&ws_o[
                (((size_t)b * nchunk + c + 1) * NH + h) * (size_t)DV + 2 * tid];
            L += w0 * ws_ml[mlb0 + 1] + w1 * ws_ml[mlb1 + 1];
            a0 = fmaf(w1, o1.x, fmaf(w0, o0.x, a0));
            a1 = fmaf(w1, o1.y, fmaf(w0, o0.y, a1));
        }
        for (; c < nact; ++c) {
            const size_t mlb = (((size_t)b * nchunk + c) * NH + h) * 2;
            const float w = exp2f(ws_ml[mlb] - M);
            L += w * ws_ml[mlb + 1];
            const float2 o = *(const float2*)&ws_o[
                (((size_t)b * nchunk + c) * NH + h) * (size_t)DV + 2 * tid];
            a0 = fmaf(w, o.x, a0);
            a1 = fmaf(w, o.y, a1);
        }
    }
    const float inv = 1.f / L;
    *(float2*)&out[((size_t)b * NH + h) * (size_t)DV + 2 * tid] =
        make_float2(a0 * inv, a1 * inv);
}

extern "C" void kernel_launch(void* const* d_in, const int* in_sizes, int n_in,
                              void* d_out, int out_size, void* d_ws, size_t ws_size,
                              hipStream_t stream)
{
    (void)in_sizes; (void)n_in; (void)out_size;
    const float* qg    = (const float*)d_in[0];   // [B,H,576]
    const float* kvnew = (const float*)d_in[1];   // [B,1,576]
    const float* cache = (const float*)d_in[2];   // [B,4096,576]
    const int*   lens  = (const int*)d_in[3];     // [B]
    float* out = (float*)d_out;                   // [B,H,512] fp32

    // nchunk=16 (chunk=256) — best measured split (R15).
    int nchunk = 16;
    while (nchunk > 1 &&
           (size_t)NB * nchunk * NH * (DV + 2) * sizeof(float) > ws_size)
        nchunk >>= 1;
    const int chunk = MAXLEN / nchunk;            // multiple of 32

    float* ws_o  = (float*)d_ws;
    float* ws_ml = ws_o + (size_t)NB * nchunk * NH * DV;

    dim3 gA(nchunk, NB);
    mla_mfma<<<gA, 256, 0, stream>>>(qg, kvnew, cache, lens, ws_o, ws_ml,
                                     nchunk, chunk);
    dim3 gB(NH, NB);
    mla_reduce<<<gB, 256, 0, stream>>>(lens, ws_o, ws_ml, out, nchunk, chunk);
}

// Round 21
// 114.732 us; speedup vs baseline: 1.7043x; 1.0115x over previous
//
#include <hip/hip_runtime.h>
#include <math.h>

// MLA decode attention, flash-decoding split + bf16 MFMA core.
// B=64, H=16, latent D=576, V=512, MAX_LEN=4096. fp32 in/out.
//
// R21 = R20 (116.1us, session best) + c-major dispatch order (tail trim).
//  - Grid swapped to (b, c): blocks now dispatch c-major, so the LAST
//    dispatched blocks are high-c chunks — active only for long sequences
//    (c=15: ~6% of batches) and then only PARTIAL (<=256 rows). Under the
//    old b-major order the last blocks could be FULL 8-round chunks of
//    batch 63, leaving a ~25-30us single-block tail. Pure index swap,
//    zero risk.
//
// Structure (locked after 21 rounds of ablation):
//  - grid (B=64, nchunk=16), 256 thr (4 waves), TR=32 rounds/chunk.
//  - Half-split register prefetch (A early / B late) -> cvtpk -> dual-write
//    K_s[32][584] row-major + Vt[512][36] transposed (bf16).
//  - 4-wave redundant scores: 2x18 mfma_f32_16x16x32_bf16, Q-frags
//    preloaded with scale*log2e folded. (Redundancy is free: falsified
//    alternatives -- kc-split, slim tiles, u16-PV -- all regressed.)
//  - Log2-domain online softmax: defer-max (THR=8), deferred l-reduction.
//  - P -> bf16 via per-wave LDS transpose; PV = 8 mfma/wave over private
//    128 v-cols from Vt (wide b64 reads).
//  - setprio(1) on MFMA clusters; OOB row clamp; LDS 79360 B (2 blk/CU).
//  - mla_reduce: flash-decoding merge, 4x/2x unrolled passes.

typedef __attribute__((ext_vector_type(8))) short bf16x8;
typedef __attribute__((ext_vector_type(4))) float f32x4;

namespace {
constexpr int NB = 64, NH = 16, MAXLEN = 4096, D = 576, DV = 512;
constexpr int KP = 584;   // K_s row stride (bf16): 1168 B rows, 16B-aligned
constexpr int VP = 36;    // Vt row stride (bf16): 72 B rows, 8B-aligned
constexpr int PP = 40;    // P_s row stride (bf16)
constexpr float SCALE_LOG2E = 0.041666666666666664f * 1.4426950408889634f;
constexpr float NEGINF = -1e30f;
constexpr float THR2 = 8.0f;  // defer-max threshold (log2 domain)
}

__device__ __forceinline__ uint32_t cvtpk(float a, float b) {
    uint32_t r;
    asm("v_cvt_pk_bf16_f32 %0, %1, %2" : "=v"(r) : "v"(a), "v"(b));
    return r;   // low16 = bf16(a), high16 = bf16(b)
}

union FragAB { bf16x8 v; uint32_t u[4]; };

__global__ __launch_bounds__(256, 2)
void mla_mfma(const float* __restrict__ qg, const float* __restrict__ kvnew,
              const float* __restrict__ cache, const int* __restrict__ lens,
              float* __restrict__ ws_o, float* __restrict__ ws_ml,
              int nchunk, int chunk)
{
    // R21: c-major dispatch — b fastest, c slowest.
    const int b = blockIdx.x, c = blockIdx.y;
    const int total = lens[b] + 1;
    const int start = c * chunk;
    if (start >= total) return;               // uniform, before any barrier
    const int end = min(start + chunk, total);
    const int newpos = total - 1;

    __shared__ short K_s[32 * KP];            // 37376 B row-major bf16
    __shared__ short V_s[DV * VP];            // 36864 B Vt[v][r] bf16
    __shared__ short P_s[4 * 16 * PP];        //  5120 B   (total 79360)

    const int tid  = (int)threadIdx.x;
    const int wave = tid >> 6, lane = tid & 63;
    const int lr = lane & 15, g = lane >> 4;

    const float* vnew = kvnew + (size_t)b * D;
    const float* cb   = cache + (size_t)b * MAXLEN * D;

    const int rg = tid >> 5;                  // staging row-group: rows rg*4+i
    const int cl = tid & 31;                  // staging col-lane

    float4 nxA[2][4];                         // early half (cols f4 0..63)
    float4 nxB[3][4];                         // late half (cols f4 64..143)

#define ROWPTRS(R0N)                                                           \
        const int gr0 = (R0N) + rg * 4;                                        \
        const int r0c = min(gr0,     MAXLEN - 1);                              \
        const int r1c = min(gr0 + 1, MAXLEN - 1);                              \
        const int r2c = min(gr0 + 2, MAXLEN - 1);                              \
        const int r3c = min(gr0 + 3, MAXLEN - 1);                              \
        const float* s0 = (gr0     == newpos) ? vnew : (cb + (size_t)r0c * D); \
        const float* s1 = (gr0 + 1 == newpos) ? vnew : (cb + (size_t)r1c * D); \
        const float* s2 = (gr0 + 2 == newpos) ? vnew : (cb + (size_t)r2c * D); \
        const float* s3 = (gr0 + 3 == newpos) ? vnew : (cb + (size_t)r3c * D);

#define STAGE_LOAD_A(R0N)                                                      \
    {                                                                          \
        ROWPTRS(R0N)                                                           \
        _Pragma("unroll")                                                      \
        for (int it = 0; it < 2; ++it) {                                       \
            const int cf = 32 * it + cl;                                       \
            nxA[it][0] = *(const float4*)(s0 + cf * 4);                        \
            nxA[it][1] = *(const float4*)(s1 + cf * 4);                        \
            nxA[it][2] = *(const float4*)(s2 + cf * 4);                        \
            nxA[it][3] = *(const float4*)(s3 + cf * 4);                        \
        }                                                                      \
    }

#define STAGE_LOAD_B(R0N)                                                      \
    {                                                                          \
        ROWPTRS(R0N)                                                           \
        _Pragma("unroll")                                                      \
        for (int jt = 0; jt < 3; ++jt) {                                       \
            const int cf = 32 * (jt + 2) + cl;                                 \
            if (cf < 144) {                                                    \
                nxB[jt][0] = *(const float4*)(s0 + cf * 4);                    \
                nxB[jt][1] = *(const float4*)(s1 + cf * 4);                    \
                nxB[jt][2] = *(const float4*)(s2 + cf * 4);                    \
                nxB[jt][3] = *(const float4*)(s3 + cf * 4);                    \
            }                                                                  \
        }                                                                      \
    }

#define WRITE_ONE(NX, CF)                                                      \
    {                                                                          \
        uint2 w;                                                               \
        w.x = cvtpk(NX[0].x, NX[0].y); w.y = cvtpk(NX[0].z, NX[0].w);          \
        *(uint2*)&K_s[(rg * 4 + 0) * KP + (CF) * 4] = w;                       \
        w.x = cvtpk(NX[1].x, NX[1].y); w.y = cvtpk(NX[1].z, NX[1].w);          \
        *(uint2*)&K_s[(rg * 4 + 1) * KP + (CF) * 4] = w;                       \
        w.x = cvtpk(NX[2].x, NX[2].y); w.y = cvtpk(NX[2].z, NX[2].w);          \
        *(uint2*)&K_s[(rg * 4 + 2) * KP + (CF) * 4] = w;                       \
        w.x = cvtpk(NX[3].x, NX[3].y); w.y = cvtpk(NX[3].z, NX[3].w);          \
        *(uint2*)&K_s[(rg * 4 + 3) * KP + (CF) * 4] = w;                       \
        if ((CF) < 128) {                                                      \
            const int v0 = (CF) * 4;                                           \
            w.x = cvtpk(NX[0].x, NX[1].x); w.y = cvtpk(NX[2].x, NX[3].x);      \
            *(uint2*)&V_s[(v0 + 0) * VP + rg * 4] = w;                         \
            w.x = cvtpk(NX[0].y, NX[1].y); w.y = cvtpk(NX[2].y, NX[3].y);      \
            *(uint2*)&V_s[(v0 + 1) * VP + rg * 4] = w;                         \
            w.x = cvtpk(NX[0].z, NX[1].z); w.y = cvtpk(NX[2].z, NX[3].z);      \
            *(uint2*)&V_s[(v0 + 2) * VP + rg * 4] = w;                         \
            w.x = cvtpk(NX[0].w, NX[1].w); w.y = cvtpk(NX[2].w, NX[3].w);      \
            *(uint2*)&V_s[(v0 + 3) * VP + rg * 4] = w;                         \
        }                                                                      \
    }

#define STAGE_WRITE_A()                                                        \
    {                                                                          \
        _Pragma("unroll")                                                      \
        for (int it = 0; it < 2; ++it) {                                       \
            const int cf = 32 * it + cl;                                       \
            WRITE_ONE(nxA[it], cf)                                             \
        }                                                                      \
    }

#define STAGE_WRITE_B()                                                        \
    {                                                                          \
        _Pragma("unroll")                                                      \
        for (int jt = 0; jt < 3; ++jt) {                                       \
            const int cf = 32 * (jt + 2) + cl;                                 \
            if (cf < 144) { WRITE_ONE(nxB[jt], cf) }                           \
        }                                                                      \
    }

    // ---- Q A-frags: lane holds Q[h=lr][kc*32 + g*8 + j], scale folded ----
    FragAB qf[18];
    {
        const float* qrow = qg + ((size_t)b * NH + lr) * D + g * 8;
        #pragma unroll
        for (int kc = 0; kc < 18; ++kc) {
            float4 x = *(const float4*)(qrow + kc * 32);
            float4 y = *(const float4*)(qrow + kc * 32 + 4);
            qf[kc].u[0] = cvtpk(x.x * SCALE_LOG2E, x.y * SCALE_LOG2E);
            qf[kc].u[1] = cvtpk(x.z * SCALE_LOG2E, x.w * SCALE_LOG2E);
            qf[kc].u[2] = cvtpk(y.x * SCALE_LOG2E, y.y * SCALE_LOG2E);
            qf[kc].u[3] = cvtpk(y.z * SCALE_LOG2E, y.w * SCALE_LOG2E);
        }
    }

    f32x4 acc[8];
    #pragma unroll
    for (int i = 0; i < 8; ++i) acc[i] = (f32x4){0.f, 0.f, 0.f, 0.f};
    float m2[4] = {NEGINF, NEGINF, NEGINF, NEGINF};
    float ll[4] = {0.f, 0.f, 0.f, 0.f};      // lane-local partial sums

    // ---- prologue: stage tile 0 ----
    STAGE_LOAD_A(start);
    STAGE_LOAD_B(start);
    STAGE_WRITE_A();
    STAGE_WRITE_B();
    __syncthreads();

    for (int r0 = start; r0 < end; r0 += 32) {
        const bool have_next = (r0 + 32 < end);     // block-uniform
        if (have_next) STAGE_LOAD_A(r0 + 32);       // early half in flight

        // ---- scores: S[16h, 32r], two 16x16 tiles ----
        f32x4 sc0 = (f32x4){0.f, 0.f, 0.f, 0.f};
        f32x4 sc1 = (f32x4){0.f, 0.f, 0.f, 0.f};
        __builtin_amdgcn_s_setprio(1);
        #pragma unroll
        for (int kc = 0; kc < 18; ++kc) {
            FragAB kb0, kb1;
            kb0.v = *(const bf16x8*)&K_s[lr * KP + kc * 32 + g * 8];
            kb1.v = *(const bf16x8*)&K_s[(16 + lr) * KP + kc * 32 + g * 8];
            sc0 = __builtin_amdgcn_mfma_f32_16x16x32_bf16(qf[kc].v, kb0.v, sc0, 0, 0, 0);
            sc1 = __builtin_amdgcn_mfma_f32_16x16x32_bf16(qf[kc].v, kb1.v, sc1, 0, 0, 0);
        }
        __builtin_amdgcn_s_setprio(0);
        // mask invalid rows (lane's D-col = row r0+lr / r0+16+lr)
        if (r0 + lr >= end)      sc0 = (f32x4){NEGINF, NEGINF, NEGINF, NEGINF};
        if (r0 + 16 + lr >= end) sc1 = (f32x4){NEGINF, NEGINF, NEGINF, NEGINF};

        // ---- online softmax (log2 domain): defer-max + deferred l ----
        float mt[4];
        int grew = 0;
        #pragma unroll
        for (int i = 0; i < 4; ++i) {
            float t = fmaxf(sc0[i], sc1[i]);
            t = fmaxf(t, __shfl_xor(t, 1));
            t = fmaxf(t, __shfl_xor(t, 2));
            t = fmaxf(t, __shfl_xor(t, 4));
            t = fmaxf(t, __shfl_xor(t, 8));
            mt[i] = t;
            grew |= (t > m2[i] + THR2) ? 1 : 0;   // defer: tolerate +8 log2
        }
        if (__any(grew)) {                   // wave-uniform, RARE
            float scl[4];
            #pragma unroll
            for (int i = 0; i < 4; ++i) {
                const float nm = fmaxf(m2[i], mt[i]);
                scl[i] = exp2f(m2[i] - nm);  // ==1 for non-growing groups
                m2[i] = nm;
                ll[i] *= scl[i];
            }
            const f32x4 scl4 = (f32x4){scl[0], scl[1], scl[2], scl[3]};
            #pragma unroll
            for (int vt = 0; vt < 8; ++vt) acc[vt] = acc[vt] * scl4;
        }
        float p0[4], p1[4];
        #pragma unroll
        for (int i = 0; i < 4; ++i) {
            p0[i] = exp2f(sc0[i] - m2[i]);   // bounded by 2^THR2
            p1[i] = exp2f(sc1[i] - m2[i]);
            ll[i] += p0[i] + p1[i];          // lane-local; reduced at epilogue
        }

        // ---- P -> bf16, per-wave LDS transpose, re-read as PV A-frag ----
        short* pw = &P_s[wave * 16 * PP];
        #pragma unroll
        for (int i = 0; i < 4; ++i) {
            pw[(4 * g + i) * PP + lr]      = (short)cvtpk(p0[i], p0[i]);
            pw[(4 * g + i) * PP + 16 + lr] = (short)cvtpk(p1[i], p1[i]);
        }
        asm volatile("s_waitcnt lgkmcnt(0)" ::: "memory");  // cross-lane RAW
        FragAB pa;
        pa.v = *(const bf16x8*)&pw[lr * PP + g * 8];

        // ---- PV: wave's 128 v-cols, 8 mfma ----
        __builtin_amdgcn_s_setprio(1);
        #pragma unroll
        for (int vt = 0; vt < 8; ++vt) {
            const int v = wave * 128 + vt * 16 + lr;
            FragAB vb;
            *(uint2*)&vb.u[0] = *(const uint2*)&V_s[v * VP + g * 8];
            *(uint2*)&vb.u[2] = *(const uint2*)&V_s[v * VP + g * 8 + 4];
            acc[vt] = __builtin_amdgcn_mfma_f32_16x16x32_bf16(pa.v, vb.v, acc[vt], 0, 0, 0);
        }
        __builtin_amdgcn_s_setprio(0);

        if (have_next) STAGE_LOAD_B(r0 + 32);   // late half issued pre-barrier
        __syncthreads();                        // all waves done reading LDS
        if (have_next) { STAGE_WRITE_A(); STAGE_WRITE_B(); }
        __syncthreads();                        // next round staged
    }

    // ---- epilogue: reduce lane-local l across the 16-lane dd-group ----
    #pragma unroll
    for (int i = 0; i < 4; ++i) {
        float s = ll[i];
        s += __shfl_xor(s, 1);
        s += __shfl_xor(s, 2);
        s += __shfl_xor(s, 4);
        s += __shfl_xor(s, 8);
        ll[i] = s;
    }

    // ---- write partials: lane covers h = 4g+i, v = wave*128 + vt*16 + lr --
    float* ob = ws_o + (((size_t)b * nchunk + c) * NH) * DV;
    #pragma unroll
    for (int vt = 0; vt < 8; ++vt) {
        const int v = wave * 128 + vt * 16 + lr;
        #pragma unroll
        for (int i = 0; i < 4; ++i)
            ob[(4 * g + i) * DV + v] = acc[vt][i];
    }
    if (wave == 0 && lr == 0) {
        float* mlb = ws_ml + ((size_t)b * nchunk + c) * NH * 2;
        #pragma unroll
        for (int i = 0; i < 4; ++i) {
            mlb[(4 * g + i) * 2]     = m2[i];   // log2-domain running max
            mlb[(4 * g + i) * 2 + 1] = ll[i];
        }
    }
#undef STAGE_LOAD_A
#undef STAGE_LOAD_B
#undef STAGE_WRITE_A
#undef STAGE_WRITE_B
#undef WRITE_ONE
#undef ROWPTRS
}

__global__ __launch_bounds__(256)
void mla_reduce(const int* __restrict__ lens,
                const float* __restrict__ ws_o,
                const float* __restrict__ ws_ml,
                float* __restrict__ out,
                int nchunk, int chunk)
{
    const int h = blockIdx.x;
    const int b = blockIdx.y;
    const int tid = (int)threadIdx.x;
    const int total = lens[b] + 1;
    const int nact = min(nchunk, (total + chunk - 1) / chunk);

    float M = NEGINF;
    {
        int c = 0;
        for (; c + 4 <= nact; c += 4) {       // 4 independent loads in flight
            const float m0 = ws_ml[(((size_t)b * nchunk + c    ) * NH + h) * 2];
            const float m1 = ws_ml[(((size_t)b * nchunk + c + 1) * NH + h) * 2];
            const float m2_ = ws_ml[(((size_t)b * nchunk + c + 2) * NH + h) * 2];
            const float m3 = ws_ml[(((size_t)b * nchunk + c + 3) * NH + h) * 2];
            M = fmaxf(M, fmaxf(fmaxf(m0, m1), fmaxf(m2_, m3)));
        }
        for (; c < nact; ++c)
            M = fmaxf(M, ws_ml[(((size_t)b * nchunk + c) * NH + h) * 2]);
    }

    float a0 = 0.f, a1 = 0.f, L = 0.f;
    {
        int c = 0;
        for (; c + 2 <= nact; c += 2) {       // 2 independent iterations
            const size_t mlb0 = (((size_t)b * nchunk + c    ) * NH + h) * 2;
            const size_t mlb1 = (((size_t)b * nchunk + c + 1) * NH + h) * 2;
            const float w0 = exp2f(ws_ml[mlb0] - M);
            const float w1 = exp2f(ws_ml[mlb1] - M);
            const float2 o0 = *(const float2*)&ws_o[
                (((size_t)b * nchunk + c    ) * NH + h) * (size_t)DV + 2 * tid];
            const float2 o1 = *(const float2*)&ws_o[
                (((size_t)b * nchunk + c + 1) * NH + h) * (size_t)DV + 2 * tid];
            L += w0 * ws_ml[mlb0 + 1] + w1 * ws_ml[mlb1 + 1];
            a0 = fmaf(w1, o1.x, fmaf(w0, o0.x, a0));
            a1 = fmaf(w1, o1.y, fmaf(w0, o0.y, a1));
        }
        for (; c < nact; ++c) {
            const size_t mlb = (((size_t)b * nchunk + c) * NH + h) * 2;
            const float w = exp2f(ws_ml[mlb] - M);
            L += w * ws_ml[mlb + 1];
            const float2 o = *(const float2*)&ws_o[
                (((size_t)b * nchunk + c) * NH + h) * (size_t)DV + 2 * tid];
            a0 = fmaf(w, o.x, a0);
            a1 = fmaf(w, o.y, a1);
        }
    }
    const float inv = 1.f / L;
    *(float2*)&out[((size_t)b * NH + h) * (size_t)DV + 2 * tid] =
        make_float2(a0 * inv, a1 * inv);
}

extern "C" void kernel_launch(void* const* d_in, const int* in_sizes, int n_in,
                              void* d_out, int out_size, void* d_ws, size_t ws_size,
                              hipStream_t stream)
{
    (void)in_sizes; (void)n_in; (void)out_size;
    const float* qg    = (const float*)d_in[0];   // [B,H,576]
    const float* kvnew = (const float*)d_in[1];   // [B,1,576]
    const float* cache = (const float*)d_in[2];   // [B,4096,576]
    const int*   lens  = (const int*)d_in[3];     // [B]
    float* out = (float*)d_out;                   // [B,H,512] fp32

    // nchunk=16 (chunk=256) — best measured split (R15).
    int nchunk = 16;
    while (nchunk > 1 &&
           (size_t)NB * nchunk * NH * (DV + 2) * sizeof(float) > ws_size)
        nchunk >>= 1;
    const int chunk = MAXLEN / nchunk;            // multiple of 32

    float* ws_o  = (float*)d_ws;
    float* ws_ml = ws_o + (size_t)NB * nchunk * NH * DV;

    // R21: c-major dispatch — last-dispatched blocks are high-c (mostly
    // inactive or short partial chunks), shrinking the end-of-kernel tail.
    dim3 gA(NB, nchunk);
    mla_mfma<<<gA, 256, 0, stream>>>(qg, kvnew, cache, lens, ws_o, ws_ml,
                                     nchunk, chunk);
    dim3 gB(NH, NB);
    mla_reduce<<<gB, 256, 0, stream>>>(lens, ws_o, ws_ml, out, nchunk, chunk);
}

// Round 22
// 114.374 us; speedup vs baseline: 1.7096x; 1.0031x over previous
//
#include <hip/hip_runtime.h>
#include <math.h>

// MLA decode attention, flash-decoding split + bf16 MFMA core.
// B=64, H=16, latent D=576, V=512, MAX_LEN=4096. fp32 in/out.
//
// FINAL (R22 = R21 verbatim, 114.7us session best, locked).
// Session: 377 -> 224 -> 182.7 -> 158.8 -> 145.6 -> 138.5 -> 117.8 ->
// 116.1 -> 114.7 us. Terminal state: latency/phase-serialization plateau
// at 2 blocks/CU; no pipe saturated; every structural lever falsified:
//  - >2 blocks/CU closed: dual K_s+Vt layout (required: R14's u16-PV bank
//    conflicts = 2.1x regression) doesn't fit 3 blocks at TR=32; TR=16
//    doubles per-round fixed costs (R18: 1.7x regression).
//  - Deeper async closed: compiler barrier-drain semantics (R4/R10/R16).
//  - Work redistribution closed: kc-split/wave-per-block regressed 35-58%.
//
// Structure:
//  - grid (B=64, nchunk=16) c-major dispatch (tail trim), 256 thr (4
//    waves), TR=32 rounds/chunk, LDS 79360 B -> 2 blocks/CU.
//  - Half-split register prefetch (A early / B late) -> cvtpk -> dual-write
//    K_s[32][584] row-major + Vt[512][36] transposed (bf16).
//  - 4-wave redundant scores: 2x18 mfma_f32_16x16x32_bf16, Q-frags
//    preloaded with scale*log2e folded.
//  - Log2-domain online softmax: defer-max (THR=8), deferred l-reduction.
//  - P -> bf16 via per-wave LDS transpose; PV = 8 mfma/wave over private
//    128 v-cols from Vt (wide b64 reads).
//  - setprio(1) on MFMA clusters; OOB row clamp.
//  - mla_reduce: flash-decoding merge, 4x/2x unrolled passes.

typedef __attribute__((ext_vector_type(8))) short bf16x8;
typedef __attribute__((ext_vector_type(4))) float f32x4;

namespace {
constexpr int NB = 64, NH = 16, MAXLEN = 4096, D = 576, DV = 512;
constexpr int KP = 584;   // K_s row stride (bf16): 1168 B rows, 16B-aligned
constexpr int VP = 36;    // Vt row stride (bf16): 72 B rows, 8B-aligned
constexpr int PP = 40;    // P_s row stride (bf16)
constexpr float SCALE_LOG2E = 0.041666666666666664f * 1.4426950408889634f;
constexpr float NEGINF = -1e30f;
constexpr float THR2 = 8.0f;  // defer-max threshold (log2 domain)
}

__device__ __forceinline__ uint32_t cvtpk(float a, float b) {
    uint32_t r;
    asm("v_cvt_pk_bf16_f32 %0, %1, %2" : "=v"(r) : "v"(a), "v"(b));
    return r;   // low16 = bf16(a), high16 = bf16(b)
}

union FragAB { bf16x8 v; uint32_t u[4]; };

__global__ __launch_bounds__(256, 2)
void mla_mfma(const float* __restrict__ qg, const float* __restrict__ kvnew,
              const float* __restrict__ cache, const int* __restrict__ lens,
              float* __restrict__ ws_o, float* __restrict__ ws_ml,
              int nchunk, int chunk)
{
    // c-major dispatch — b fastest, c slowest (tail trim).
    const int b = blockIdx.x, c = blockIdx.y;
    const int total = lens[b] + 1;
    const int start = c * chunk;
    if (start >= total) return;               // uniform, before any barrier
    const int end = min(start + chunk, total);
    const int newpos = total - 1;

    __shared__ short K_s[32 * KP];            // 37376 B row-major bf16
    __shared__ short V_s[DV * VP];            // 36864 B Vt[v][r] bf16
    __shared__ short P_s[4 * 16 * PP];        //  5120 B   (total 79360)

    const int tid  = (int)threadIdx.x;
    const int wave = tid >> 6, lane = tid & 63;
    const int lr = lane & 15, g = lane >> 4;

    const float* vnew = kvnew + (size_t)b * D;
    const float* cb   = cache + (size_t)b * MAXLEN * D;

    const int rg = tid >> 5;                  // staging row-group: rows rg*4+i
    const int cl = tid & 31;                  // staging col-lane

    float4 nxA[2][4];                         // early half (cols f4 0..63)
    float4 nxB[3][4];                         // late half (cols f4 64..143)

#define ROWPTRS(R0N)                                                           \
        const int gr0 = (R0N) + rg * 4;                                        \
        const int r0c = min(gr0,     MAXLEN - 1);                              \
        const int r1c = min(gr0 + 1, MAXLEN - 1);                              \
        const int r2c = min(gr0 + 2, MAXLEN - 1);                              \
        const int r3c = min(gr0 + 3, MAXLEN - 1);                              \
        const float* s0 = (gr0     == newpos) ? vnew : (cb + (size_t)r0c * D); \
        const float* s1 = (gr0 + 1 == newpos) ? vnew : (cb + (size_t)r1c * D); \
        const float* s2 = (gr0 + 2 == newpos) ? vnew : (cb + (size_t)r2c * D); \
        const float* s3 = (gr0 + 3 == newpos) ? vnew : (cb + (size_t)r3c * D);

#define STAGE_LOAD_A(R0N)                                                      \
    {                                                                          \
        ROWPTRS(R0N)                                                           \
        _Pragma("unroll")                                                      \
        for (int it = 0; it < 2; ++it) {                                       \
            const int cf = 32 * it + cl;                                       \
            nxA[it][0] = *(const float4*)(s0 + cf * 4);                        \
            nxA[it][1] = *(const float4*)(s1 + cf * 4);                        \
            nxA[it][2] = *(const float4*)(s2 + cf * 4);                        \
            nxA[it][3] = *(const float4*)(s3 + cf * 4);                        \
        }                                                                      \
    }

#define STAGE_LOAD_B(R0N)                                                      \
    {                                                                          \
        ROWPTRS(R0N)                                                           \
        _Pragma("unroll")                                                      \
        for (int jt = 0; jt < 3; ++jt) {                                       \
            const int cf = 32 * (jt + 2) + cl;                                 \
            if (cf < 144) {                                                    \
                nxB[jt][0] = *(const float4*)(s0 + cf * 4);                    \
                nxB[jt][1] = *(const float4*)(s1 + cf * 4);                    \
                nxB[jt][2] = *(const float4*)(s2 + cf * 4);                    \
                nxB[jt][3] = *(const float4*)(s3 + cf * 4);                    \
            }                                                                  \
        }                                                                      \
    }

#define WRITE_ONE(NX, CF)                                                      \
    {                                                                          \
        uint2 w;                                                               \
        w.x = cvtpk(NX[0].x, NX[0].y); w.y = cvtpk(NX[0].z, NX[0].w);          \
        *(uint2*)&K_s[(rg * 4 + 0) * KP + (CF) * 4] = w;                       \
        w.x = cvtpk(NX[1].x, NX[1].y); w.y = cvtpk(NX[1].z, NX[1].w);          \
        *(uint2*)&K_s[(rg * 4 + 1) * KP + (CF) * 4] = w;                       \
        w.x = cvtpk(NX[2].x, NX[2].y); w.y = cvtpk(NX[2].z, NX[2].w);          \
        *(uint2*)&K_s[(rg * 4 + 2) * KP + (CF) * 4] = w;                       \
        w.x = cvtpk(NX[3].x, NX[3].y); w.y = cvtpk(NX[3].z, NX[3].w);          \
        *(uint2*)&K_s[(rg * 4 + 3) * KP + (CF) * 4] = w;                       \
        if ((CF) < 128) {                                                      \
            const int v0 = (CF) * 4;                                           \
            w.x = cvtpk(NX[0].x, NX[1].x); w.y = cvtpk(NX[2].x, NX[3].x);      \
            *(uint2*)&V_s[(v0 + 0) * VP + rg * 4] = w;                         \
            w.x = cvtpk(NX[0].y, NX[1].y); w.y = cvtpk(NX[2].y, NX[3].y);      \
            *(uint2*)&V_s[(v0 + 1) * VP + rg * 4] = w;                         \
            w.x = cvtpk(NX[0].z, NX[1].z); w.y = cvtpk(NX[2].z, NX[3].z);      \
            *(uint2*)&V_s[(v0 + 2) * VP + rg * 4] = w;                         \
            w.x = cvtpk(NX[0].w, NX[1].w); w.y = cvtpk(NX[2].w, NX[3].w);      \
            *(uint2*)&V_s[(v0 + 3) * VP + rg * 4] = w;                         \
        }                                                                      \
    }

#define STAGE_WRITE_A()                                                        \
    {                                                                          \
        _Pragma("unroll")                                                      \
        for (int it = 0; it < 2; ++it) {                                       \
            const int cf = 32 * it + cl;                                       \
            WRITE_ONE(nxA[it], cf)                                             \
        }                                                                      \
    }

#define STAGE_WRITE_B()                                                        \
    {                                                                          \
        _Pragma("unroll")                                                      \
        for (int jt = 0; jt < 3; ++jt) {                                       \
            const int cf = 32 * (jt + 2) + cl;                                 \
            if (cf < 144) { WRITE_ONE(nxB[jt], cf) }                           \
        }                                                                      \
    }

    // ---- Q A-frags: lane holds Q[h=lr][kc*32 + g*8 + j], scale folded ----
    FragAB qf[18];
    {
        const float* qrow = qg + ((size_t)b * NH + lr) * D + g * 8;
        #pragma unroll
        for (int kc = 0; kc < 18; ++kc) {
            float4 x = *(const float4*)(qrow + kc * 32);
            float4 y = *(const float4*)(qrow + kc * 32 + 4);
            qf[kc].u[0] = cvtpk(x.x * SCALE_LOG2E, x.y * SCALE_LOG2E);
            qf[kc].u[1] = cvtpk(x.z * SCALE_LOG2E, x.w * SCALE_LOG2E);
            qf[kc].u[2] = cvtpk(y.x * SCALE_LOG2E, y.y * SCALE_LOG2E);
            qf[kc].u[3] = cvtpk(y.z * SCALE_LOG2E, y.w * SCALE_LOG2E);
        }
    }

    f32x4 acc[8];
    #pragma unroll
    for (int i = 0; i < 8; ++i) acc[i] = (f32x4){0.f, 0.f, 0.f, 0.f};
    float m2[4] = {NEGINF, NEGINF, NEGINF, NEGINF};
    float ll[4] = {0.f, 0.f, 0.f, 0.f};      // lane-local partial sums

    // ---- prologue: stage tile 0 ----
    STAGE_LOAD_A(start);
    STAGE_LOAD_B(start);
    STAGE_WRITE_A();
    STAGE_WRITE_B();
    __syncthreads();

    for (int r0 = start; r0 < end; r0 += 32) {
        const bool have_next = (r0 + 32 < end);     // block-uniform
        if (have_next) STAGE_LOAD_A(r0 + 32);       // early half in flight

        // ---- scores: S[16h, 32r], two 16x16 tiles ----
        f32x4 sc0 = (f32x4){0.f, 0.f, 0.f, 0.f};
        f32x4 sc1 = (f32x4){0.f, 0.f, 0.f, 0.f};
        __builtin_amdgcn_s_setprio(1);
        #pragma unroll
        for (int kc = 0; kc < 18; ++kc) {
            FragAB kb0, kb1;
            kb0.v = *(const bf16x8*)&K_s[lr * KP + kc * 32 + g * 8];
            kb1.v = *(const bf16x8*)&K_s[(16 + lr) * KP + kc * 32 + g * 8];
            sc0 = __builtin_amdgcn_mfma_f32_16x16x32_bf16(qf[kc].v, kb0.v, sc0, 0, 0, 0);
            sc1 = __builtin_amdgcn_mfma_f32_16x16x32_bf16(qf[kc].v, kb1.v, sc1, 0, 0, 0);
        }
        __builtin_amdgcn_s_setprio(0);
        // mask invalid rows (lane's D-col = row r0+lr / r0+16+lr)
        if (r0 + lr >= end)      sc0 = (f32x4){NEGINF, NEGINF, NEGINF, NEGINF};
        if (r0 + 16 + lr >= end) sc1 = (f32x4){NEGINF, NEGINF, NEGINF, NEGINF};

        // ---- online softmax (log2 domain): defer-max + deferred l ----
        float mt[4];
        int grew = 0;
        #pragma unroll
        for (int i = 0; i < 4; ++i) {
            float t = fmaxf(sc0[i], sc1[i]);
            t = fmaxf(t, __shfl_xor(t, 1));
            t = fmaxf(t, __shfl_xor(t, 2));
            t = fmaxf(t, __shfl_xor(t, 4));
            t = fmaxf(t, __shfl_xor(t, 8));
            mt[i] = t;
            grew |= (t > m2[i] + THR2) ? 1 : 0;   // defer: tolerate +8 log2
        }
        if (__any(grew)) {                   // wave-uniform, RARE
            float scl[4];
            #pragma unroll
            for (int i = 0; i < 4; ++i) {
                const float nm = fmaxf(m2[i], mt[i]);
                scl[i] = exp2f(m2[i] - nm);  // ==1 for non-growing groups
                m2[i] = nm;
                ll[i] *= scl[i];
            }
            const f32x4 scl4 = (f32x4){scl[0], scl[1], scl[2], scl[3]};
            #pragma unroll
            for (int vt = 0; vt < 8; ++vt) acc[vt] = acc[vt] * scl4;
        }
        float p0[4], p1[4];
        #pragma unroll
        for (int i = 0; i < 4; ++i) {
            p0[i] = exp2f(sc0[i] - m2[i]);   // bounded by 2^THR2
            p1[i] = exp2f(sc1[i] - m2[i]);
            ll[i] += p0[i] + p1[i];          // lane-local; reduced at epilogue
        }

        // ---- P -> bf16, per-wave LDS transpose, re-read as PV A-frag ----
        short* pw = &P_s[wave * 16 * PP];
        #pragma unroll
        for (int i = 0; i < 4; ++i) {
            pw[(4 * g + i) * PP + lr]      = (short)cvtpk(p0[i], p0[i]);
            pw[(4 * g + i) * PP + 16 + lr] = (short)cvtpk(p1[i], p1[i]);
        }
        asm volatile("s_waitcnt lgkmcnt(0)" ::: "memory");  // cross-lane RAW
        FragAB pa;
        pa.v = *(const bf16x8*)&pw[lr * PP + g * 8];

        // ---- PV: wave's 128 v-cols, 8 mfma ----
        __builtin_amdgcn_s_setprio(1);
        #pragma unroll
        for (int vt = 0; vt < 8; ++vt) {
            const int v = wave * 128 + vt * 16 + lr;
            FragAB vb;
            *(uint2*)&vb.u[0] = *(const uint2*)&V_s[v * VP + g * 8];
            *(uint2*)&vb.u[2] = *(const uint2*)&V_s[v * VP + g * 8 + 4];
            acc[vt] = __builtin_amdgcn_mfma_f32_16x16x32_bf16(pa.v, vb.v, acc[vt], 0, 0, 0);
        }
        __builtin_amdgcn_s_setprio(0);

        if (have_next) STAGE_LOAD_B(r0 + 32);   // late half issued pre-barrier
        __syncthreads();                        // all waves done reading LDS
        if (have_next) { STAGE_WRITE_A(); STAGE_WRITE_B(); }
        __syncthreads();                        // next round staged
    }

    // ---- epilogue: reduce lane-local l across the 16-lane dd-group ----
    #pragma unroll
    for (int i = 0; i < 4; ++i) {
        float s = ll[i];
        s += __shfl_xor(s, 1);
        s += __shfl_xor(s, 2);
        s += __shfl_xor(s, 4);
        s += __shfl_xor(s, 8);
        ll[i] = s;
    }

    // ---- write partials: lane covers h = 4g+i, v = wave*128 + vt*16 + lr --
    float* ob = ws_o + (((size_t)b * nchunk + c) * NH) * DV;
    #pragma unroll
    for (int vt = 0; vt < 8; ++vt) {
        const int v = wave * 128 + vt * 16 + lr;
        #pragma unroll
        for (int i = 0; i < 4; ++i)
            ob[(4 * g + i) * DV + v] = acc[vt][i];
    }
    if (wave == 0 && lr == 0) {
        float* mlb = ws_ml + ((size_t)b * nchunk + c) * NH * 2;
        #pragma unroll
        for (int i = 0; i < 4; ++i) {
            mlb[(4 * g + i) * 2]     = m2[i];   // log2-domain running max
            mlb[(4 * g + i) * 2 + 1] = ll[i];
        }
    }
#undef STAGE_LOAD_A
#undef STAGE_LOAD_B
#undef STAGE_WRITE_A
#undef STAGE_WRITE_B
#undef WRITE_ONE
#undef ROWPTRS
}

__global__ __launch_bounds__(256)
void mla_reduce(const int* __restrict__ lens,
                const float* __restrict__ ws_o,
                const float* __restrict__ ws_ml,
                float* __restrict__ out,
                int nchunk, int chunk)
{
    const int h = blockIdx.x;
    const int b = blockIdx.y;
    const int tid = (int)threadIdx.x;
    const int total = lens[b] + 1;
    const int nact = min(nchunk, (total + chunk - 1) / chunk);

    float M = NEGINF;
    {
        int c = 0;
        for (; c + 4 <= nact; c += 4) {       // 4 independent loads in flight
            const float m0 = ws_ml[(((size_t)b * nchunk + c    ) * NH + h) * 2];
            const float m1 = ws_ml[(((size_t)b * nchunk + c + 1) * NH + h) * 2];
            const float m2_ = ws_ml[(((size_t)b * nchunk + c + 2) * NH + h) * 2];
            const float m3 = ws_ml[(((size_t)b * nchunk + c + 3) * NH + h) * 2];
            M = fmaxf(M, fmaxf(fmaxf(m0, m1), fmaxf(m2_, m3)));
        }
        for (; c < nact; ++c)
            M = fmaxf(M, ws_ml[(((size_t)b * nchunk + c) * NH + h) * 2]);
    }

    float a0 = 0.f, a1 = 0.f, L = 0.f;
    {
        int c = 0;
        for (; c + 2 <= nact; c += 2) {       // 2 independent iterations
            const size_t mlb0 = (((size_t)b * nchunk + c    ) * NH + h) * 2;
            const size_t mlb1 = (((size_t)b * nchunk + c + 1) * NH + h) * 2;
            const float w0 = exp2f(ws_ml[mlb0] - M);
            const float w1 = exp2f(ws_ml[mlb1] - M);
            const float2 o0 = *(const float2*)&ws_o[
                (((size_t)b * nchunk + c    ) * NH + h) * (size_t)DV + 2 * tid];
            const float2 o1 = *(const float2*)&ws_o[
                (((size_t)b * nchunk + c + 1) * NH + h) * (size_t)DV + 2 * tid];
            L += w0 * ws_ml[mlb0 + 1] + w1 * ws_ml[mlb1 + 1];
            a0 = fmaf(w1, o1.x, fmaf(w0, o0.x, a0));
            a1 = fmaf(w1, o1.y, fmaf(w0, o0.y, a1));
        }
        for (; c < nact; ++c) {
            const size_t mlb = (((size_t)b * nchunk + c) * NH + h) * 2;
            const float w = exp2f(ws_ml[mlb] - M);
            L += w * ws_ml[mlb + 1];
            const float2 o = *(const float2*)&ws_o[
                (((size_t)b * nchunk + c) * NH + h) * (size_t)DV + 2 * tid];
            a0 = fmaf(w, o.x, a0);
            a1 = fmaf(w, o.y, a1);
        }
    }
    const float inv = 1.f / L;
    *(float2*)&out[((size_t)b * NH + h) * (size_t)DV + 2 * tid] =
        make_float2(a0 * inv, a1 * inv);
}

extern "C" void kernel_launch(void* const* d_in, const int* in_sizes, int n_in,
                              void* d_out, int out_size, void* d_ws, size_t ws_size,
                              hipStream_t stream)
{
    (void)in_sizes; (void)n_in; (void)out_size;
    const float* qg    = (const float*)d_in[0];   // [B,H,576]
    const float* kvnew = (const float*)d_in[1];   // [B,1,576]
    const float* cache = (const float*)d_in[2];   // [B,4096,576]
    const int*   lens  = (const int*)d_in[3];     // [B]
    float* out = (float*)d_out;                   // [B,H,512] fp32

    // nchunk=16 (chunk=256) — best measured split (R15).
    int nchunk = 16;
    while (nchunk > 1 &&
           (size_t)NB * nchunk * NH * (DV + 2) * sizeof(float) > ws_size)
        nchunk >>= 1;
    const int chunk = MAXLEN / nchunk;            // multiple of 32

    float* ws_o  = (float*)d_ws;
    float* ws_ml = ws_o + (size_t)NB * nchunk * NH * DV;

    // c-major dispatch — last-dispatched blocks are high-c (mostly inactive
    // or short partial chunks), shrinking the end-of-kernel tail.
    dim3 gA(NB, nchunk);
    mla_mfma<<<gA, 256, 0, stream>>>(qg, kvnew, cache, lens, ws_o, ws_ml,
                                     nchunk, chunk);
    dim3 gB(NH, NB);
    mla_reduce<<<gB, 256, 0, stream>>>(lens, ws_o, ws_ml, out, nchunk, chunk);
}